// Round 13
// baseline (331.300 us; speedup 1.0000x reference)
//
#include <hip/hip_runtime.h>
#include <stdint.h>

#define D 128
#define NCLS 64
#define BSH 8       // 256 nodes per bucket
#define BNODES 256
#define BMASK 255
#define NBMAX 1024  // max buckets
#define CCHUNK 4096 // edges per scatter chunk (16/thread in regs)
#define HISTB 256   // histogram grid
#define GB1 1664    // gemm blocks co-launched with scatter
#define GB2 1664    // gemm blocks co-launched with bbuild

typedef __bf16 bf16x8 __attribute__((ext_vector_type(8)));
typedef float f32x4 __attribute__((ext_vector_type(4)));
typedef float f32x2 __attribute__((ext_vector_type(2)));

union B8 { uint4 u; bf16x8 v; };

// pack 8 f32 -> 8 bf16 fragment
__device__ __forceinline__ B8 pack8(const float4& a, const float4& b) {
  union { __bf16 h[8]; uint4 u; } p;
  p.h[0] = (__bf16)a.x; p.h[1] = (__bf16)a.y; p.h[2] = (__bf16)a.z; p.h[3] = (__bf16)a.w;
  p.h[4] = (__bf16)b.x; p.h[5] = (__bf16)b.y; p.h[6] = (__bf16)b.z; p.h[7] = (__bf16)b.w;
  B8 r; r.u = p.u; return r;
}

// store 4 accumulator rows (same col) as fp8 via HW packed converts
__device__ __forceinline__ void store_fp8_rows(unsigned char* __restrict__ Z,
                                               const f32x4& acc, int row0, int col, int N) {
  const int p01 = __builtin_amdgcn_cvt_pk_fp8_f32(acc[0], acc[1], 0, false);
  const int p23 = __builtin_amdgcn_cvt_pk_fp8_f32(acc[2], acc[3], 0, false);
  const unsigned char b0 = (unsigned char)(p01 & 0xff);
  const unsigned char b1 = (unsigned char)((p01 >> 8) & 0xff);
  const unsigned char b2 = (unsigned char)(p23 & 0xff);
  const unsigned char b3 = (unsigned char)((p23 >> 8) & 0xff);
  if (row0 + 0 < N) Z[(size_t)(row0 + 0) * D + col] = b0;
  if (row0 + 1 < N) Z[(size_t)(row0 + 1) * D + col] = b1;
  if (row0 + 2 < N) Z[(size_t)(row0 + 2) * D + col] = b2;
  if (row0 + 3 < N) Z[(size_t)(row0 + 3) * D + col] = b3;
}

// ---- shared device body: z1 = feat(f32) @ W1^T tiles [t0, t1) ------------

__device__ __forceinline__ void gemm_z1_range(const float* __restrict__ feat,
                                              const float* __restrict__ W1,
                                              unsigned char* __restrict__ Z,
                                              int N, int t0, int t1,
                                              int bid, int nblk, int tid) {
  const int wave = tid >> 6;
  const int lane = tid & 63;
  const int l15 = lane & 15;
  const int quad = lane >> 4;

  B8 bfrag[2][4];
#pragma unroll
  for (int t = 0; t < 2; ++t) {
    const int n = wave * 32 + t * 16 + l15;
    const float* wp = W1 + (size_t)n * D + quad * 8;
#pragma unroll
    for (int ks = 0; ks < 4; ++ks)
      bfrag[t][ks] = pack8(*reinterpret_cast<const float4*>(wp + ks * 32),
                           *reinterpret_cast<const float4*>(wp + ks * 32 + 4));
  }

  for (int mt = t0 + bid; mt < t1; mt += nblk) {
    const int arow = min(mt * 16 + l15, N - 1);
    const float* ap = feat + (size_t)arow * D + quad * 8;
    B8 a[4];
#pragma unroll
    for (int ks = 0; ks < 4; ++ks)
      a[ks] = pack8(*reinterpret_cast<const float4*>(ap + ks * 32),
                    *reinterpret_cast<const float4*>(ap + ks * 32 + 4));
#pragma unroll
    for (int t = 0; t < 2; ++t) {
      f32x4 acc = {0.f, 0.f, 0.f, 0.f};
#pragma unroll
      for (int ks = 0; ks < 4; ++ks)
        acc = __builtin_amdgcn_mfma_f32_16x16x32_bf16(a[ks].v, bfrag[t][ks].v, acc, 0, 0, 0);
      store_fp8_rows(Z, acc, mt * 16 + quad * 4, wave * 32 + t * 16 + l15, N);
    }
  }
}

// ---- k_hist: bucket histogram (standalone, ~7us) -------------------------

__global__ __launch_bounds__(256) void k_hist(const int* __restrict__ dst,
                                              int* __restrict__ bcnt, int E, int NB) {
  __shared__ int h[NBMAX];
  for (int i = threadIdx.x; i < NB; i += 256) h[i] = 0;
  __syncthreads();
  for (int e = blockIdx.x * 256 + threadIdx.x; e < E; e += HISTB * 256)
    atomicAdd(&h[dst[e] >> BSH], 1);
  __syncthreads();
  for (int i = threadIdx.x; i < NB; i += 256) {
    int c = h[i];
    if (c) atomicAdd(&bcnt[i], c);
  }
}

__global__ __launch_bounds__(1024) void k_bscan(const int* __restrict__ bcnt,
                                                int* __restrict__ bbase,
                                                int* __restrict__ bcur, int NB, int E) {
  __shared__ int sm[NBMAX];
  const int tid = threadIdx.x;
  int v = (tid < NB) ? bcnt[tid] : 0;
  sm[tid] = v;
  __syncthreads();
  for (int off = 1; off < NBMAX; off <<= 1) {
    int t = (tid >= off) ? sm[tid - off] : 0;
    __syncthreads();
    sm[tid] += t;
    __syncthreads();
  }
  if (tid < NB) {
    bbase[tid] = sm[tid] - v;
    bcur[tid] = sm[tid] - v;
  }
  if (tid == 0) bbase[NB] = E;
}

// ---- k_sg1: role-split { scatter chunks | gemmz1 tiles [0,T1) } ----------

__global__ __launch_bounds__(256) void k_sg1(const int* __restrict__ src,
                                             const int* __restrict__ dst,
                                             int* __restrict__ bcur,
                                             int* __restrict__ ebuck,
                                             const float* __restrict__ feat,
                                             const float* __restrict__ W1,
                                             unsigned char* __restrict__ Z,
                                             int N, int E, int NB, int scb, int t1) {
  __shared__ int h[NBMAX];
  __shared__ int base[NBMAX];
  const int tid = threadIdx.x;
  if ((int)blockIdx.x >= scb) {
    gemm_z1_range(feat, W1, Z, N, 0, t1, blockIdx.x - scb, GB1, tid);
    return;
  }
  // ---- register-staged scatter chunk ----
  const int beg = blockIdx.x * CCHUNK;
  const int end = min(beg + CCHUNK, E);
  int d[16];
#pragma unroll
  for (int i = 0; i < 16; ++i) {
    const int e = beg + i * 256 + tid;
    d[i] = (e < end) ? dst[e] : -1;
  }
  for (int i = tid; i < NB; i += 256) h[i] = 0;
  __syncthreads();
#pragma unroll
  for (int i = 0; i < 16; ++i)
    if (d[i] >= 0) atomicAdd(&h[d[i] >> BSH], 1);
  __syncthreads();
  for (int i = tid; i < NB; i += 256) {
    const int c = h[i];
    base[i] = c ? atomicAdd(&bcur[i], c) : 0;
    h[i] = 0;  // becomes local rank cursor
  }
  __syncthreads();
#pragma unroll
  for (int i = 0; i < 16; ++i) {
    if (d[i] >= 0) {
      const int e = beg + i * 256 + tid;
      const int b = d[i] >> BSH;
      const int r = atomicAdd(&h[b], 1);
      ebuck[base[b] + r] = (src[e] << BSH) | (d[i] & BMASK);
    }
  }
}

// ---- k_bg2: role-split { bbuild buckets | gemmz1 tiles [T1, mtiles) } ----

__global__ __launch_bounds__(256) void k_bg2(const int* __restrict__ ebuck,
                                             const int* __restrict__ bbase,
                                             int* __restrict__ row_ptr,
                                             int* __restrict__ esrc,
                                             float* __restrict__ inv,
                                             const float* __restrict__ feat,
                                             const float* __restrict__ W1,
                                             unsigned char* __restrict__ Z,
                                             int N, int E, int NB, int t1) {
  __shared__ int cnt[BNODES], s[BNODES], cur[BNODES];
  const int tid = threadIdx.x;
  if ((int)blockIdx.x >= NB) {
    const int mtiles = (N + 15) >> 4;
    gemm_z1_range(feat, W1, Z, N, t1, mtiles, blockIdx.x - NB, GB2, tid);
    return;
  }
  // ---- per-bucket CSR build (256-node bucket, 16-reg stage + tail) ----
  const int b = blockIdx.x;
  const int n0 = b << BSH;
  const int nn = min(BNODES, N - n0);
  const int beg = bbase[b], end = bbase[b + 1];
  int v[16];
#pragma unroll
  for (int i = 0; i < 16; ++i) {
    const int e = beg + i * 256 + tid;
    v[i] = (e < end) ? ebuck[e] : -1;
  }
  cnt[tid] = 0;
  __syncthreads();
#pragma unroll
  for (int i = 0; i < 16; ++i)
    if (v[i] >= 0) atomicAdd(&cnt[v[i] & BMASK], 1);
  for (int e = beg + 4096 + tid; e < end; e += 256)
    atomicAdd(&cnt[ebuck[e] & BMASK], 1);
  __syncthreads();
  s[tid] = cnt[tid];
  __syncthreads();
  for (int off = 1; off < BNODES; off <<= 1) {
    const int t = (tid >= off) ? s[tid - off] : 0;
    __syncthreads();
    s[tid] += t;
    __syncthreads();
  }
  {
    const int ex = s[tid] - cnt[tid];
    cur[tid] = ex;
    if (tid < nn) {
      row_ptr[n0 + tid] = beg + ex;
      inv[n0 + tid] = 1.0f / fmaxf((float)cnt[tid], 1.0f);
    }
  }
  if (b == 0 && tid == 0) row_ptr[N] = E;
  __syncthreads();
#pragma unroll
  for (int i = 0; i < 16; ++i)
    if (v[i] >= 0) {
      const int r = atomicAdd(&cur[v[i] & BMASK], 1);
      esrc[beg + r] = v[i] >> BSH;
    }
  for (int e = beg + 4096 + tid; e < end; e += 256) {
    const int p = ebuck[e];
    const int r = atomicAdd(&cur[p & BMASK], 1);
    esrc[beg + r] = p >> BSH;
  }
}

// ---- z2 = h1(bf16) @ W2^T, fp8 out via HW pk converts --------------------

__global__ __launch_bounds__(256) void k_gemmz2(const ushort* __restrict__ A,
                                                const float* __restrict__ W,
                                                unsigned char* __restrict__ Z, int N) {
  const int wave = threadIdx.x >> 6;
  const int lane = threadIdx.x & 63;
  const int l15 = lane & 15;
  const int quad = lane >> 4;

  B8 bfrag[2][4];
#pragma unroll
  for (int t = 0; t < 2; ++t) {
    const int n = wave * 32 + t * 16 + l15;
    const float* wp = W + (size_t)n * D + quad * 8;
#pragma unroll
    for (int ks = 0; ks < 4; ++ks)
      bfrag[t][ks] = pack8(*reinterpret_cast<const float4*>(wp + ks * 32),
                           *reinterpret_cast<const float4*>(wp + ks * 32 + 4));
  }

  const int mtiles = (N + 15) >> 4;
  for (int mt = blockIdx.x; mt < mtiles; mt += gridDim.x) {
    const int arow = min(mt * 16 + l15, N - 1);
    const ushort* ap = A + (size_t)arow * D + quad * 8;
    B8 a[4];
#pragma unroll
    for (int ks = 0; ks < 4; ++ks)
      a[ks].u = *reinterpret_cast<const uint4*>(ap + ks * 32);
#pragma unroll
    for (int t = 0; t < 2; ++t) {
      f32x4 acc = {0.f, 0.f, 0.f, 0.f};
#pragma unroll
      for (int ks = 0; ks < 4; ++ks)
        acc = __builtin_amdgcn_mfma_f32_16x16x32_bf16(a[ks].v, bfrag[t][ks].v, acc, 0, 0, 0);
      store_fp8_rows(Z, acc, mt * 16 + quad * 4, wave * 32 + t * 16 + l15, N);
    }
  }
}

// ---- gather core: fp8 rows, HW packed unpack, pipelined index loads ------

__device__ __forceinline__ void accq8pk(f32x2 acc[4], const uint2& u) {
  acc[0] += __builtin_amdgcn_cvt_pk_f32_fp8((int)u.x, false);
  acc[1] += __builtin_amdgcn_cvt_pk_f32_fp8((int)u.x, true);
  acc[2] += __builtin_amdgcn_cvt_pk_f32_fp8((int)u.y, false);
  acc[3] += __builtin_amdgcn_cvt_pk_f32_fp8((int)u.y, true);
}

__device__ __forceinline__ void gather_acc8(const unsigned char* __restrict__ hp,
                                            const int* __restrict__ esrc,
                                            int beg, int end, f32x2 acc[4]) {
  const int n4 = (end - beg) >> 2;
  int e = beg;
  if (n4 > 0) {
    int4 ss = *reinterpret_cast<const int4*>(esrc + e);
    for (int it = 0; it < n4; ++it) {
      const uint2 u0 = *reinterpret_cast<const uint2*>(hp + (size_t)ss.x * D);
      const uint2 u1 = *reinterpret_cast<const uint2*>(hp + (size_t)ss.y * D);
      const uint2 u2 = *reinterpret_cast<const uint2*>(hp + (size_t)ss.z * D);
      const uint2 u3 = *reinterpret_cast<const uint2*>(hp + (size_t)ss.w * D);
      e += 4;
      if (it + 1 < n4) ss = *reinterpret_cast<const int4*>(esrc + e);  // next idx in flight
      accq8pk(acc, u0);
      accq8pk(acc, u1);
      accq8pk(acc, u2);
      accq8pk(acc, u3);
    }
  }
  for (; e < end; ++e) {
    const uint2 u0 = *reinterpret_cast<const uint2*>(hp + (size_t)esrc[e] * D);
    accq8pk(acc, u0);
  }
}

// ---- h = relu(mean_gather(z_fp8) + bias) -- barrier-free pure gather -----

__global__ __launch_bounds__(256) void k_gather_relu(const unsigned char* __restrict__ z,
                                                     const int* __restrict__ row_ptr,
                                                     const int* __restrict__ esrc,
                                                     const float* __restrict__ inv,
                                                     const float* __restrict__ bias,
                                                     ushort* __restrict__ out, int N) {
  const int g = threadIdx.x >> 4;
  const int w = threadIdx.x & 15;
  const unsigned char* hp = z + w * 8;
  float bb[8];
  {
    const float4 x = *reinterpret_cast<const float4*>(bias + w * 8);
    const float4 y = *reinterpret_cast<const float4*>(bias + w * 8 + 4);
    bb[0] = x.x; bb[1] = x.y; bb[2] = x.z; bb[3] = x.w;
    bb[4] = y.x; bb[5] = y.y; bb[6] = y.z; bb[7] = y.w;
  }
  const int ntiles = (N + 15) >> 4;
  for (int tile = blockIdx.x; tile < ntiles; tile += gridDim.x) {
    const int node = tile * 16 + g;
    if (node >= N) continue;
    f32x2 acc[4] = {{0.f, 0.f}, {0.f, 0.f}, {0.f, 0.f}, {0.f, 0.f}};
    gather_acc8(hp, esrc, row_ptr[node], row_ptr[node + 1], acc);
    const float iv = inv[node];
    union { __bf16 b[8]; uint4 u; } p;
#pragma unroll
    for (int i = 0; i < 4; ++i) {
      p.b[i * 2 + 0] = (__bf16)fmaxf(acc[i].x * iv + bb[i * 2 + 0], 0.f);
      p.b[i * 2 + 1] = (__bf16)fmaxf(acc[i].y * iv + bb[i * 2 + 1], 0.f);
    }
    *reinterpret_cast<uint4*>(out + (size_t)node * D + w * 8) = p.u;
  }
}

// ---- logits: wave-independent, no LDS, no barriers (R7, proven) ----------

__global__ __launch_bounds__(256, 2) void k_logits(const ushort* __restrict__ h1,
                                                   const ushort* __restrict__ h2,
                                                   const float* __restrict__ Wl,
                                                   const float* __restrict__ bl,
                                                   float* __restrict__ out, int N) {
  const int lane = threadIdx.x & 63;
  const int l15 = lane & 15;
  const int quad = lane >> 4;
  const int wid = blockIdx.x * 4 + (threadIdx.x >> 6);
  const int nw = gridDim.x * 4;

  B8 wfrag[4][8];
  float blv[4];
#pragma unroll
  for (int t = 0; t < 4; ++t) {
    const int n = t * 16 + l15;
    blv[t] = bl[n];
    const float* wp = Wl + (size_t)n * (2 * D) + quad * 8;
#pragma unroll
    for (int ks = 0; ks < 8; ++ks)
      wfrag[t][ks] = pack8(*reinterpret_cast<const float4*>(wp + ks * 32),
                           *reinterpret_cast<const float4*>(wp + ks * 32 + 4));
  }

  const int mtiles = (N + 15) >> 4;
  for (int mt = wid; mt < mtiles; mt += nw) {
    const int arow = min(mt * 16 + l15, N - 1);
    const ushort* p1 = h1 + (size_t)arow * D + quad * 8;
    const ushort* p2 = h2 + (size_t)arow * D + quad * 8;
    B8 a1[4], a2[4];
#pragma unroll
    for (int ks = 0; ks < 4; ++ks) {
      a1[ks].u = *reinterpret_cast<const uint4*>(p1 + ks * 32);
      a2[ks].u = *reinterpret_cast<const uint4*>(p2 + ks * 32);
    }
    f32x4 acc[4];
#pragma unroll
    for (int t = 0; t < 4; ++t) acc[t] = f32x4{0.f, 0.f, 0.f, 0.f};
#pragma unroll
    for (int ks = 0; ks < 4; ++ks)
#pragma unroll
      for (int t = 0; t < 4; ++t)
        acc[t] = __builtin_amdgcn_mfma_f32_16x16x32_bf16(a1[ks].v, wfrag[t][ks].v, acc[t], 0, 0, 0);
#pragma unroll
    for (int ks = 0; ks < 4; ++ks)
#pragma unroll
      for (int t = 0; t < 4; ++t)
        acc[t] = __builtin_amdgcn_mfma_f32_16x16x32_bf16(a2[ks].v, wfrag[t][4 + ks].v, acc[t], 0, 0, 0);
#pragma unroll
    for (int t = 0; t < 4; ++t)
#pragma unroll
      for (int r = 0; r < 4; ++r)
        acc[t][r] += blv[t];
#pragma unroll
    for (int r = 0; r < 4; ++r) {
      float m = fmaxf(fmaxf(acc[0][r], acc[1][r]), fmaxf(acc[2][r], acc[3][r]));
#pragma unroll
      for (int off = 8; off > 0; off >>= 1) m = fmaxf(m, __shfl_xor(m, off));
      const float e0 = __expf(acc[0][r] - m);
      const float e1 = __expf(acc[1][r] - m);
      const float e2 = __expf(acc[2][r] - m);
      const float e3 = __expf(acc[3][r] - m);
      float s = (e0 + e1) + (e2 + e3);
#pragma unroll
      for (int off = 8; off > 0; off >>= 1) s += __shfl_xor(s, off);
      const float ls = m + __logf(s);
      const int orow = mt * 16 + quad * 4 + r;
      if (orow < N) {
        float* op = out + (size_t)orow * NCLS + l15;
#pragma unroll
        for (int t = 0; t < 4; ++t) op[t * 16] = acc[t][r] - ls;
      }
    }
  }
}

// ---- driver --------------------------------------------------------------

extern "C" void kernel_launch(void* const* d_in, const int* in_sizes, int n_in,
                              void* d_out, int out_size, void* d_ws, size_t ws_size,
                              hipStream_t stream) {
  const float* feat = (const float*)d_in[0];
  const int* src = (const int*)d_in[1];
  const int* dst = (const int*)d_in[2];
  const float* W1 = (const float*)d_in[3];
  const float* b1 = (const float*)d_in[4];
  const float* W2 = (const float*)d_in[5];
  const float* b2 = (const float*)d_in[6];
  const float* Wl = (const float*)d_in[7];
  const float* bl = (const float*)d_in[8];
  float* out = (float*)d_out;

  const int N = in_sizes[0] / D;  // 100000
  const int E = in_sizes[1];      // 1600000
  const int NB = (N + BNODES - 1) >> BSH;  // 391
  const int SCB = (E + CCHUNK - 1) / CCHUNK;  // 391
  const int mtiles = (N + 15) >> 4;  // 6250
  const int T1 = (mtiles * 4) / 7;   // ~3571: z1 tiles done alongside scatter

  // workspace layout (identical to R8/R11/R12 proven layout)
  float* ws = (float*)d_ws;
  float* inv = ws;                               // N f32
  ushort* h1b = (ushort*)(inv + N);              // N*D bf16
  ushort* h2b = h1b + (size_t)N * D;             // N*D bf16
  unsigned char* z8 = (unsigned char*)(h2b + (size_t)N * D);  // N*D fp8
  int* row_ptr = (int*)(z8 + (size_t)N * D);     // N+1
  int* esrc = row_ptr + N + 1;                   // E
  int* ebuck = esrc + E;                         // E
  int* bcnt = ebuck + E;                         // NBMAX
  int* bbase = bcnt + NBMAX;                     // NBMAX+1
  int* bcur = bbase + NBMAX + 1;                 // NBMAX

  hipMemsetAsync(bcnt, 0, NBMAX * sizeof(int), stream);

  // CSR chain with gemmz1 slid underneath (z1 independent of CSR)
  k_hist<<<HISTB, 256, 0, stream>>>(dst, bcnt, E, NB);
  k_bscan<<<1, 1024, 0, stream>>>(bcnt, bbase, bcur, NB, E);
  k_sg1<<<SCB + GB1, 256, 0, stream>>>(src, dst, bcur, ebuck, feat, W1, z8,
                                       N, E, NB, SCB, T1);
  k_bg2<<<NB + GB2, 256, 0, stream>>>(ebuck, bbase, row_ptr, esrc, inv,
                                      feat, W1, z8, N, E, NB, T1);

  // layer 1: pure gather with relu epilogue
  k_gather_relu<<<2048, 256, 0, stream>>>(z8, row_ptr, esrc, inv, b1, h1b, N);

  // layer 2: project h1 (overwrites z8 after gather1 drained it), pure gather
  k_gemmz2<<<2048, 256, 0, stream>>>(h1b, W2, z8, N);
  k_gather_relu<<<2048, 256, 0, stream>>>(z8, row_ptr, esrc, inv, b2, h2b, N);

  // logits + log_softmax
  k_logits<<<512, 256, 0, stream>>>(h1b, h2b, Wl, bl, out, N);
}

// Round 14
// 316.245 us; speedup vs baseline: 1.0476x; 1.0476x over previous
//
#include <hip/hip_runtime.h>
#include <stdint.h>

#define D 128
#define NCLS 64
#define BSH 8       // 256 nodes per bucket
#define BNODES 256
#define BMASK 255
#define NBMAX 1024  // max buckets
#define CCHUNK 4096 // edges per k_bscatter block (16/thread in regs)
#define HISTB 256   // histogram blocks inside k_pre
#define GEMMB 2048  // gemmz1 blocks inside k_pre

typedef __bf16 bf16x8 __attribute__((ext_vector_type(8)));
typedef float f32x4 __attribute__((ext_vector_type(4)));
typedef float f32x2 __attribute__((ext_vector_type(2)));

union B8 { uint4 u; bf16x8 v; };

// pack 8 f32 -> 8 bf16 fragment
__device__ __forceinline__ B8 pack8(const float4& a, const float4& b) {
  union { __bf16 h[8]; uint4 u; } p;
  p.h[0] = (__bf16)a.x; p.h[1] = (__bf16)a.y; p.h[2] = (__bf16)a.z; p.h[3] = (__bf16)a.w;
  p.h[4] = (__bf16)b.x; p.h[5] = (__bf16)b.y; p.h[6] = (__bf16)b.z; p.h[7] = (__bf16)b.w;
  B8 r; r.u = p.u; return r;
}

// store 4 accumulator rows (same col) as fp8 via HW packed converts
__device__ __forceinline__ void store_fp8_rows(unsigned char* __restrict__ Z,
                                               const f32x4& acc, int row0, int col, int N) {
  const int p01 = __builtin_amdgcn_cvt_pk_fp8_f32(acc[0], acc[1], 0, false);
  const int p23 = __builtin_amdgcn_cvt_pk_fp8_f32(acc[2], acc[3], 0, false);
  const unsigned char b0 = (unsigned char)(p01 & 0xff);
  const unsigned char b1 = (unsigned char)((p01 >> 8) & 0xff);
  const unsigned char b2 = (unsigned char)(p23 & 0xff);
  const unsigned char b3 = (unsigned char)((p23 >> 8) & 0xff);
  if (row0 + 0 < N) Z[(size_t)(row0 + 0) * D + col] = b0;
  if (row0 + 1 < N) Z[(size_t)(row0 + 1) * D + col] = b1;
  if (row0 + 2 < N) Z[(size_t)(row0 + 2) * D + col] = b2;
  if (row0 + 3 < N) Z[(size_t)(row0 + 3) * D + col] = b3;
}

// ---- k_pre: role-split { bucket histogram | z1 = feat @ W1^T fp8 } -------
// GEMM path: 2 M-tiles per iteration, both A-fragments loaded before any
// MFMA -> 16 independent 16B loads in flight (was 8) to cover latency.

__global__ __launch_bounds__(256) void k_pre(const int* __restrict__ dst,
                                             const float* __restrict__ feat,
                                             const float* __restrict__ W1,
                                             int* __restrict__ bcnt,
                                             unsigned char* __restrict__ Z,
                                             int N, int E, int NB) {
  __shared__ int h[NBMAX];
  if (blockIdx.x < HISTB) {
    for (int i = threadIdx.x; i < NB; i += 256) h[i] = 0;
    __syncthreads();
    for (int e = blockIdx.x * 256 + threadIdx.x; e < E; e += HISTB * 256)
      atomicAdd(&h[dst[e] >> BSH], 1);
    __syncthreads();
    for (int i = threadIdx.x; i < NB; i += 256) {
      int c = h[i];
      if (c) atomicAdd(&bcnt[i], c);
    }
    return;
  }
  const int bid = blockIdx.x - HISTB;
  const int wave = threadIdx.x >> 6;
  const int lane = threadIdx.x & 63;
  const int l15 = lane & 15;
  const int quad = lane >> 4;

  B8 bfrag[2][4];
#pragma unroll
  for (int t = 0; t < 2; ++t) {
    const int n = wave * 32 + t * 16 + l15;
    const float* wp = W1 + (size_t)n * D + quad * 8;
#pragma unroll
    for (int ks = 0; ks < 4; ++ks)
      bfrag[t][ks] = pack8(*reinterpret_cast<const float4*>(wp + ks * 32),
                           *reinterpret_cast<const float4*>(wp + ks * 32 + 4));
  }

  const int mtiles = (N + 15) >> 4;
  const int pairs = (mtiles + 1) >> 1;
  for (int p = bid; p < pairs; p += GEMMB) {
    const int mt0 = p * 2;
    const int mt1 = p * 2 + 1;
    const int arow0 = min(mt0 * 16 + l15, N - 1);
    const int arow1 = min(mt1 * 16 + l15, N - 1);
    const float* ap0 = feat + (size_t)arow0 * D + quad * 8;
    const float* ap1 = feat + (size_t)arow1 * D + quad * 8;
    B8 a0[4], a1[4];
#pragma unroll
    for (int ks = 0; ks < 4; ++ks)
      a0[ks] = pack8(*reinterpret_cast<const float4*>(ap0 + ks * 32),
                     *reinterpret_cast<const float4*>(ap0 + ks * 32 + 4));
#pragma unroll
    for (int ks = 0; ks < 4; ++ks)
      a1[ks] = pack8(*reinterpret_cast<const float4*>(ap1 + ks * 32),
                     *reinterpret_cast<const float4*>(ap1 + ks * 32 + 4));
#pragma unroll
    for (int t = 0; t < 2; ++t) {
      f32x4 acc = {0.f, 0.f, 0.f, 0.f};
#pragma unroll
      for (int ks = 0; ks < 4; ++ks)
        acc = __builtin_amdgcn_mfma_f32_16x16x32_bf16(a0[ks].v, bfrag[t][ks].v, acc, 0, 0, 0);
      store_fp8_rows(Z, acc, mt0 * 16 + quad * 4, wave * 32 + t * 16 + l15, N);
    }
    if (mt1 < mtiles) {
#pragma unroll
      for (int t = 0; t < 2; ++t) {
        f32x4 acc = {0.f, 0.f, 0.f, 0.f};
#pragma unroll
        for (int ks = 0; ks < 4; ++ks)
          acc = __builtin_amdgcn_mfma_f32_16x16x32_bf16(a1[ks].v, bfrag[t][ks].v, acc, 0, 0, 0);
        store_fp8_rows(Z, acc, mt1 * 16 + quad * 4, wave * 32 + t * 16 + l15, N);
      }
    }
  }
}

// ---- bucketed CSR build --------------------------------------------------

__global__ __launch_bounds__(1024) void k_bscan(const int* __restrict__ bcnt,
                                                int* __restrict__ bbase,
                                                int* __restrict__ bcur, int NB, int E) {
  __shared__ int sm[NBMAX];
  const int tid = threadIdx.x;
  int v = (tid < NB) ? bcnt[tid] : 0;
  sm[tid] = v;
  __syncthreads();
  for (int off = 1; off < NBMAX; off <<= 1) {
    int t = (tid >= off) ? sm[tid - off] : 0;
    __syncthreads();
    sm[tid] += t;
    __syncthreads();
  }
  if (tid < NB) {
    bbase[tid] = sm[tid] - v;
    bcur[tid] = sm[tid] - v;
  }
  if (tid == 0) bbase[NB] = E;
}

// register-staged scatter: dst read once into 16 regs; 391 blocks
__global__ __launch_bounds__(256) void k_bscatter(const int* __restrict__ src,
                                                  const int* __restrict__ dst,
                                                  int* __restrict__ bcur,
                                                  int* __restrict__ ebuck, int E, int NB) {
  __shared__ int h[NBMAX];
  __shared__ int base[NBMAX];
  const int tid = threadIdx.x;
  const int beg = blockIdx.x * CCHUNK;
  const int end = min(beg + CCHUNK, E);
  int d[16];
#pragma unroll
  for (int i = 0; i < 16; ++i) {
    const int e = beg + i * 256 + tid;
    d[i] = (e < end) ? dst[e] : -1;
  }
  for (int i = tid; i < NB; i += 256) h[i] = 0;
  __syncthreads();
#pragma unroll
  for (int i = 0; i < 16; ++i)
    if (d[i] >= 0) atomicAdd(&h[d[i] >> BSH], 1);
  __syncthreads();
  for (int i = tid; i < NB; i += 256) {
    const int c = h[i];
    base[i] = c ? atomicAdd(&bcur[i], c) : 0;
    h[i] = 0;  // becomes local rank cursor
  }
  __syncthreads();
#pragma unroll
  for (int i = 0; i < 16; ++i) {
    if (d[i] >= 0) {
      const int e = beg + i * 256 + tid;
      const int b = d[i] >> BSH;
      const int r = atomicAdd(&h[b], 1);
      ebuck[base[b] + r] = (src[e] << BSH) | (d[i] & BMASK);
    }
  }
}

// per-bucket CSR for 256-node buckets (16 regs = 4096 cap + overflow tail)
__global__ __launch_bounds__(256) void k_bbuild(const int* __restrict__ ebuck,
                                                const int* __restrict__ bbase,
                                                int* __restrict__ row_ptr,
                                                int* __restrict__ esrc,
                                                float* __restrict__ inv, int N, int E) {
  __shared__ int cnt[BNODES], s[BNODES], cur[BNODES];
  const int b = blockIdx.x;
  const int n0 = b << BSH;
  const int nn = min(BNODES, N - n0);
  const int beg = bbase[b], end = bbase[b + 1];
  const int tid = threadIdx.x;
  int v[16];
#pragma unroll
  for (int i = 0; i < 16; ++i) {
    const int e = beg + i * 256 + tid;
    v[i] = (e < end) ? ebuck[e] : -1;
  }
  cnt[tid] = 0;
  __syncthreads();
#pragma unroll
  for (int i = 0; i < 16; ++i)
    if (v[i] >= 0) atomicAdd(&cnt[v[i] & BMASK], 1);
  for (int e = beg + 4096 + tid; e < end; e += 256)
    atomicAdd(&cnt[ebuck[e] & BMASK], 1);
  __syncthreads();
  s[tid] = cnt[tid];
  __syncthreads();
  for (int off = 1; off < BNODES; off <<= 1) {
    const int t = (tid >= off) ? s[tid - off] : 0;
    __syncthreads();
    s[tid] += t;
    __syncthreads();
  }
  {
    const int ex = s[tid] - cnt[tid];
    cur[tid] = ex;
    if (tid < nn) {
      row_ptr[n0 + tid] = beg + ex;
      inv[n0 + tid] = 1.0f / fmaxf((float)cnt[tid], 1.0f);
    }
  }
  if (b == 0 && tid == 0) row_ptr[N] = E;
  __syncthreads();
#pragma unroll
  for (int i = 0; i < 16; ++i)
    if (v[i] >= 0) {
      const int r = atomicAdd(&cur[v[i] & BMASK], 1);
      esrc[beg + r] = v[i] >> BSH;
    }
  for (int e = beg + 4096 + tid; e < end; e += 256) {
    const int p = ebuck[e];
    const int r = atomicAdd(&cur[p & BMASK], 1);
    esrc[beg + r] = p >> BSH;
  }
}

// ---- z2 = h1(bf16) @ W2^T, fp8 out via HW pk converts --------------------

__global__ __launch_bounds__(256) void k_gemmz2(const ushort* __restrict__ A,
                                                const float* __restrict__ W,
                                                unsigned char* __restrict__ Z, int N) {
  const int wave = threadIdx.x >> 6;
  const int lane = threadIdx.x & 63;
  const int l15 = lane & 15;
  const int quad = lane >> 4;

  B8 bfrag[2][4];
#pragma unroll
  for (int t = 0; t < 2; ++t) {
    const int n = wave * 32 + t * 16 + l15;
    const float* wp = W + (size_t)n * D + quad * 8;
#pragma unroll
    for (int ks = 0; ks < 4; ++ks)
      bfrag[t][ks] = pack8(*reinterpret_cast<const float4*>(wp + ks * 32),
                           *reinterpret_cast<const float4*>(wp + ks * 32 + 4));
  }

  const int mtiles = (N + 15) >> 4;
  for (int mt = blockIdx.x; mt < mtiles; mt += gridDim.x) {
    const int arow = min(mt * 16 + l15, N - 1);
    const ushort* ap = A + (size_t)arow * D + quad * 8;
    B8 a[4];
#pragma unroll
    for (int ks = 0; ks < 4; ++ks)
      a[ks].u = *reinterpret_cast<const uint4*>(ap + ks * 32);
#pragma unroll
    for (int t = 0; t < 2; ++t) {
      f32x4 acc = {0.f, 0.f, 0.f, 0.f};
#pragma unroll
      for (int ks = 0; ks < 4; ++ks)
        acc = __builtin_amdgcn_mfma_f32_16x16x32_bf16(a[ks].v, bfrag[t][ks].v, acc, 0, 0, 0);
      store_fp8_rows(Z, acc, mt * 16 + quad * 4, wave * 32 + t * 16 + l15, N);
    }
  }
}

// ---- gather core: fp8 rows, HW packed unpack, pipelined index loads ------

__device__ __forceinline__ void accq8pk(f32x2 acc[4], const uint2& u) {
  acc[0] += __builtin_amdgcn_cvt_pk_f32_fp8((int)u.x, false);
  acc[1] += __builtin_amdgcn_cvt_pk_f32_fp8((int)u.x, true);
  acc[2] += __builtin_amdgcn_cvt_pk_f32_fp8((int)u.y, false);
  acc[3] += __builtin_amdgcn_cvt_pk_f32_fp8((int)u.y, true);
}

__device__ __forceinline__ void gather_acc8(const unsigned char* __restrict__ hp,
                                            const int* __restrict__ esrc,
                                            int beg, int end, f32x2 acc[4]) {
  const int n4 = (end - beg) >> 2;
  int e = beg;
  if (n4 > 0) {
    int4 ss = *reinterpret_cast<const int4*>(esrc + e);
    for (int it = 0; it < n4; ++it) {
      const uint2 u0 = *reinterpret_cast<const uint2*>(hp + (size_t)ss.x * D);
      const uint2 u1 = *reinterpret_cast<const uint2*>(hp + (size_t)ss.y * D);
      const uint2 u2 = *reinterpret_cast<const uint2*>(hp + (size_t)ss.z * D);
      const uint2 u3 = *reinterpret_cast<const uint2*>(hp + (size_t)ss.w * D);
      e += 4;
      if (it + 1 < n4) ss = *reinterpret_cast<const int4*>(esrc + e);  // next idx in flight
      accq8pk(acc, u0);
      accq8pk(acc, u1);
      accq8pk(acc, u2);
      accq8pk(acc, u3);
    }
  }
  for (; e < end; ++e) {
    const uint2 u0 = *reinterpret_cast<const uint2*>(hp + (size_t)esrc[e] * D);
    accq8pk(acc, u0);
  }
}

// ---- h = relu(mean_gather(z_fp8) + bias) -- barrier-free pure gather -----

__global__ __launch_bounds__(256) void k_gather_relu(const unsigned char* __restrict__ z,
                                                     const int* __restrict__ row_ptr,
                                                     const int* __restrict__ esrc,
                                                     const float* __restrict__ inv,
                                                     const float* __restrict__ bias,
                                                     ushort* __restrict__ out, int N) {
  const int g = threadIdx.x >> 4;
  const int w = threadIdx.x & 15;
  const unsigned char* hp = z + w * 8;
  float bb[8];
  {
    const float4 x = *reinterpret_cast<const float4*>(bias + w * 8);
    const float4 y = *reinterpret_cast<const float4*>(bias + w * 8 + 4);
    bb[0] = x.x; bb[1] = x.y; bb[2] = x.z; bb[3] = x.w;
    bb[4] = y.x; bb[5] = y.y; bb[6] = y.z; bb[7] = y.w;
  }
  const int ntiles = (N + 15) >> 4;
  for (int tile = blockIdx.x; tile < ntiles; tile += gridDim.x) {
    const int node = tile * 16 + g;
    if (node >= N) continue;
    f32x2 acc[4] = {{0.f, 0.f}, {0.f, 0.f}, {0.f, 0.f}, {0.f, 0.f}};
    gather_acc8(hp, esrc, row_ptr[node], row_ptr[node + 1], acc);
    const float iv = inv[node];
    union { __bf16 b[8]; uint4 u; } p;
#pragma unroll
    for (int i = 0; i < 4; ++i) {
      p.b[i * 2 + 0] = (__bf16)fmaxf(acc[i].x * iv + bb[i * 2 + 0], 0.f);
      p.b[i * 2 + 1] = (__bf16)fmaxf(acc[i].y * iv + bb[i * 2 + 1], 0.f);
    }
    *reinterpret_cast<uint4*>(out + (size_t)node * D + w * 8) = p.u;
  }
}

// ---- logits: wave-independent, no LDS, no barriers (R7, proven) ----------

__global__ __launch_bounds__(256, 2) void k_logits(const ushort* __restrict__ h1,
                                                   const ushort* __restrict__ h2,
                                                   const float* __restrict__ Wl,
                                                   const float* __restrict__ bl,
                                                   float* __restrict__ out, int N) {
  const int lane = threadIdx.x & 63;
  const int l15 = lane & 15;
  const int quad = lane >> 4;
  const int wid = blockIdx.x * 4 + (threadIdx.x >> 6);
  const int nw = gridDim.x * 4;

  B8 wfrag[4][8];
  float blv[4];
#pragma unroll
  for (int t = 0; t < 4; ++t) {
    const int n = t * 16 + l15;
    blv[t] = bl[n];
    const float* wp = Wl + (size_t)n * (2 * D) + quad * 8;
#pragma unroll
    for (int ks = 0; ks < 8; ++ks)
      wfrag[t][ks] = pack8(*reinterpret_cast<const float4*>(wp + ks * 32),
                           *reinterpret_cast<const float4*>(wp + ks * 32 + 4));
  }

  const int mtiles = (N + 15) >> 4;
  for (int mt = wid; mt < mtiles; mt += nw) {
    const int arow = min(mt * 16 + l15, N - 1);
    const ushort* p1 = h1 + (size_t)arow * D + quad * 8;
    const ushort* p2 = h2 + (size_t)arow * D + quad * 8;
    B8 a1[4], a2[4];
#pragma unroll
    for (int ks = 0; ks < 4; ++ks) {
      a1[ks].u = *reinterpret_cast<const uint4*>(p1 + ks * 32);
      a2[ks].u = *reinterpret_cast<const uint4*>(p2 + ks * 32);
    }
    f32x4 acc[4];
#pragma unroll
    for (int t = 0; t < 4; ++t) acc[t] = f32x4{0.f, 0.f, 0.f, 0.f};
#pragma unroll
    for (int ks = 0; ks < 4; ++ks)
#pragma unroll
      for (int t = 0; t < 4; ++t)
        acc[t] = __builtin_amdgcn_mfma_f32_16x16x32_bf16(a1[ks].v, wfrag[t][ks].v, acc[t], 0, 0, 0);
#pragma unroll
    for (int ks = 0; ks < 4; ++ks)
#pragma unroll
      for (int t = 0; t < 4; ++t)
        acc[t] = __builtin_amdgcn_mfma_f32_16x16x32_bf16(a2[ks].v, wfrag[t][4 + ks].v, acc[t], 0, 0, 0);
#pragma unroll
    for (int t = 0; t < 4; ++t)
#pragma unroll
      for (int r = 0; r < 4; ++r)
        acc[t][r] += blv[t];
#pragma unroll
    for (int r = 0; r < 4; ++r) {
      float m = fmaxf(fmaxf(acc[0][r], acc[1][r]), fmaxf(acc[2][r], acc[3][r]));
#pragma unroll
      for (int off = 8; off > 0; off >>= 1) m = fmaxf(m, __shfl_xor(m, off));
      const float e0 = __expf(acc[0][r] - m);
      const float e1 = __expf(acc[1][r] - m);
      const float e2 = __expf(acc[2][r] - m);
      const float e3 = __expf(acc[3][r] - m);
      float s = (e0 + e1) + (e2 + e3);
#pragma unroll
      for (int off = 8; off > 0; off >>= 1) s += __shfl_xor(s, off);
      const float ls = m + __logf(s);
      const int orow = mt * 16 + quad * 4 + r;
      if (orow < N) {
        float* op = out + (size_t)orow * NCLS + l15;
#pragma unroll
        for (int t = 0; t < 4; ++t) op[t * 16] = acc[t][r] - ls;
      }
    }
  }
}

// ---- driver --------------------------------------------------------------

extern "C" void kernel_launch(void* const* d_in, const int* in_sizes, int n_in,
                              void* d_out, int out_size, void* d_ws, size_t ws_size,
                              hipStream_t stream) {
  const float* feat = (const float*)d_in[0];
  const int* src = (const int*)d_in[1];
  const int* dst = (const int*)d_in[2];
  const float* W1 = (const float*)d_in[3];
  const float* b1 = (const float*)d_in[4];
  const float* W2 = (const float*)d_in[5];
  const float* b2 = (const float*)d_in[6];
  const float* Wl = (const float*)d_in[7];
  const float* bl = (const float*)d_in[8];
  float* out = (float*)d_out;

  const int N = in_sizes[0] / D;  // 100000
  const int E = in_sizes[1];      // 1600000
  const int NB = (N + BNODES - 1) >> BSH;  // 391

  // workspace layout (identical to R8/R11/R12 proven layout)
  float* ws = (float*)d_ws;
  float* inv = ws;                               // N f32
  ushort* h1b = (ushort*)(inv + N);              // N*D bf16
  ushort* h2b = h1b + (size_t)N * D;             // N*D bf16
  unsigned char* z8 = (unsigned char*)(h2b + (size_t)N * D);  // N*D fp8
  int* row_ptr = (int*)(z8 + (size_t)N * D);     // N+1
  int* esrc = row_ptr + N + 1;                   // E
  int* ebuck = esrc + E;                         // E
  int* bcnt = ebuck + E;                         // NBMAX
  int* bbase = bcnt + NBMAX;                     // NBMAX+1
  int* bcur = bbase + NBMAX + 1;                 // NBMAX

  hipMemsetAsync(bcnt, 0, NBMAX * sizeof(int), stream);

  // role-split: bucket histogram || z1 projection (2-tile pipelined)
  k_pre<<<HISTB + GEMMB, 256, 0, stream>>>(dst, feat, W1, bcnt, z8, N, E, NB);

  // bucketed CSR (256-node buckets, register-staged)
  k_bscan<<<1, 1024, 0, stream>>>(bcnt, bbase, bcur, NB, E);
  k_bscatter<<<(E + CCHUNK - 1) / CCHUNK, 256, 0, stream>>>(src, dst, bcur, ebuck, E, NB);
  k_bbuild<<<NB, 256, 0, stream>>>(ebuck, bbase, row_ptr, esrc, inv, N, E);

  // layer 1: pure gather with relu epilogue
  k_gather_relu<<<2048, 256, 0, stream>>>(z8, row_ptr, esrc, inv, b1, h1b, N);

  // layer 2: project h1 (overwrites z8 after gather1 drained it), pure gather
  k_gemmz2<<<2048, 256, 0, stream>>>(h1b, W2, z8, N);
  k_gather_relu<<<2048, 256, 0, stream>>>(z8, row_ptr, esrc, inv, b2, h2b, N);

  // logits + log_softmax
  k_logits<<<512, 256, 0, stream>>>(h1b, h2b, Wl, bl, out, N);
}